// Round 19
// baseline (298.057 us; speedup 1.0000x reference)
//
#include <hip/hip_runtime.h>
#include <cstdint>

#define T_STEPS 200
#define B_TOTAL 8192
#define F_IN    40
#define H_DIM   128
#define C_OUT   5

#define CH      4                         // time steps per staged chunk
#define NCHUNK  (T_STEPS / CH)            // 50
#define CHB     (CH * F_IN * 4)           // 640 bytes per chunk per b
#define WIN     1024                      // staged window bytes (1 gload)
#define ROWB    (T_STEPS * F_IN * 4)      // 32000 bytes per b

typedef float v2f __attribute__((ext_vector_type(2)));
typedef float v4f __attribute__((ext_vector_type(4)));

// v_pk_fma_f32: per-word IEEE fp32 FMA (bit-identical to v_fma_f32).
// op_sel broadcasts one word of the x-pair to both result words:
// LO -> word0 (x_f), HI -> word1 (x_{f+1}).  Validated bit-exact r6-r18.
// NOTE (r18 model): pk is HALF-RATE on gfx950 (4 cyc/wave64) — it saves
// issue slots, not FMA-pipe cycles. Kernel is near the FMA-pipe bound.
#define PKFMA_LO(acc, xp, wp)                                                  \
    asm("v_pk_fma_f32 %0, %1, %2, %0 op_sel:[0,0,0] op_sel_hi:[0,1,1]"        \
        : "+v"(acc) : "v"(xp), "v"(wp))
#define PKFMA_HI(acc, xp, wp)                                                  \
    asm("v_pk_fma_f32 %0, %1, %2, %0 op_sel:[1,0,0] op_sel_hi:[1,1,1]"        \
        : "+v"(acc) : "v"(xp), "v"(wp))

// async global->LDS, 16B per lane, dest = wave-uniform base + lane*16
__device__ __forceinline__ void gload_lds16(const void* g, void* l) {
    __builtin_amdgcn_global_load_lds(
        (const __attribute__((address_space(1))) void*)g,
        (__attribute__((address_space(3))) void*)l, 16, 0, 0);
}

// ---------------------------------------------------------------------------
// Kernel 0: pre-interleave w1 into the pk-FMA lane layout:
// wpairs[li*40 + f] = ( w1[li][f], w1[li+64][f] ).
// ---------------------------------------------------------------------------
__global__ __launch_bounds__(256)
void prep_w(const float* __restrict__ w1, v2f* __restrict__ wpairs)
{
    const int i = blockIdx.x * 256 + threadIdx.x;     // [0, 64*40)
    if (i < 64 * F_IN) {
        const int li = i / F_IN, f = i % F_IN;
        v2f p;
        p.x = w1[li * F_IN + f];
        p.y = w1[(li + 64) * F_IN + f];
        wpairs[i] = p;
    }
}

// ---------------------------------------------------------------------------
// Kernel A: layer-1 recurrence. Exact fp32 numerics (validated r2/r5-r18):
// per-step sequential-f FMA chain (f = 0..39), +b1, then ((0.9*m)+cur)-reset,
// each op individually rounded. One wave per b; lane li owns h=li (acc.x)
// and h=li+64 (acc.y). Occupancy experiment vs r18 (else identical):
// LDS per block 16->8 KB (CH=4, WIN=1024) and no launch_bounds min-waves
// hint — if the 34% idle was ds_read latency under low residency, this
// compresses it; if flat, we are at the half-rate-pk FMA-pipe bound.
// ---------------------------------------------------------------------------
__global__ __launch_bounds__(256)
void snn_l1(const float* __restrict__ x,
            const v2f* __restrict__ wpairs,
            const float* __restrict__ b1,
            ulonglong2* __restrict__ masks)
{
    __shared__ __align__(16) char xs[2][4][WIN];   // 8 KiB

    const int li = threadIdx.x & 63;
    const int wv = threadIdx.x >> 6;
    const int b  = blockIdx.x * 4 + wv;
    const int hA = li, hB = li + 64;

    // weight pairs, already interleaved: wab[f] = (wA_f, wB_f)
    v2f wab[F_IN];
    {
        const v2f* wb = wpairs + li * F_IN;
#pragma unroll
        for (int f = 0; f < F_IN; ++f) wab[f] = wb[f];
    }
    const float b1A = b1[hA], b1B = b1[hB];
    float mA = 0.0f, mB = 0.0f, rA = 0.0f, rB = 0.0f;

    // per-lane global src: row base + lane*16
    const char* xb = (const char*)x + (size_t)b * ROWB + (size_t)li * 16;

    // window start in bytes for chunk c (last window shifted back, in-bounds)
    auto winstart = [](int c) { return (c == NCHUNK - 1) ? (ROWB - WIN) : c * CHB; };

    // stage chunk 0 into buffer 0
    gload_lds16(xb + winstart(0), &xs[0][wv][0]);
    asm volatile("s_waitcnt vmcnt(0)" ::: "memory");

    ulonglong2* mp = masks + b;                    // strength-reduced store ptr

    for (int c = 0; c < NCHUNK; ++c) {
        // prefetch next chunk into the other buffer (issue early, wait late)
        if (c + 1 < NCHUNK) {
            gload_lds16(xb + winstart(c + 1), &xs[(c + 1) & 1][wv][0]);
        }
        const int delta = c * CHB - winstart(c);   // 0, except last chunk
        const char* xsw = &xs[c & 1][wv][0];

#pragma unroll
        for (int sp = 0; sp < CH; sp += 2) {
            const v4f* xr0 = (const v4f*)(xsw + delta + (sp + 0) * (F_IN * 4));
            const v4f* xr1 = (const v4f*)(xsw + delta + (sp + 1) * (F_IN * 4));
            v2f acc0 = {0.0f, 0.0f};
            v2f acc1 = {0.0f, 0.0f};
            // Two independent sequential-f chains (steps sp, sp+1) in flight;
            // within each chain the f-order is 0..39 -> bit-exact.
#pragma unroll
            for (int q = 0; q < 10; ++q) {
                const v4f x0 = xr0[q];             // ds_read_b128 broadcast
                const v4f x1 = xr1[q];
                const v2f x0lo = x0.lo, x0hi = x0.hi;
                const v2f x1lo = x1.lo, x1hi = x1.hi;
                PKFMA_LO(acc0, x0lo, wab[4*q+0]);
                PKFMA_LO(acc1, x1lo, wab[4*q+0]);
                PKFMA_HI(acc0, x0lo, wab[4*q+1]);
                PKFMA_HI(acc1, x1lo, wab[4*q+1]);
                PKFMA_LO(acc0, x0hi, wab[4*q+2]);
                PKFMA_LO(acc1, x1hi, wab[4*q+2]);
                PKFMA_HI(acc0, x0hi, wab[4*q+3]);
                PKFMA_HI(acc1, x1hi, wab[4*q+3]);
            }
            // step sp
            mA = __fsub_rn(__fadd_rn(__fmul_rn(0.9f, mA), __fadd_rn(acc0.x, b1A)), rA);
            mB = __fsub_rn(__fadd_rn(__fmul_rn(0.9f, mB), __fadd_rn(acc0.y, b1B)), rB);
            bool sA = mA > 1.0f, sB = mB > 1.0f;
            rA = sA ? 1.0f : 0.0f;
            rB = sB ? 1.0f : 0.0f;
            unsigned long long lo = __ballot(sA);
            unsigned long long hi = __ballot(sB);
            if (li == 0) *mp = make_ulonglong2(lo, hi);
            mp += B_TOTAL;
            // step sp+1
            mA = __fsub_rn(__fadd_rn(__fmul_rn(0.9f, mA), __fadd_rn(acc1.x, b1A)), rA);
            mB = __fsub_rn(__fadd_rn(__fmul_rn(0.9f, mB), __fadd_rn(acc1.y, b1B)), rB);
            sA = mA > 1.0f; sB = mB > 1.0f;
            rA = sA ? 1.0f : 0.0f;
            rB = sB ? 1.0f : 0.0f;
            lo = __ballot(sA);
            hi = __ballot(sB);
            if (li == 0) *mp = make_ulonglong2(lo, hi);
            mp += B_TOTAL;
        }
        // prefetch must have landed before we read the other buffer
        asm volatile("s_waitcnt vmcnt(0)" ::: "memory");
    }
}

// ---------------------------------------------------------------------------
// Kernel B: cur2 sums, parallel over (t,b). Ascending-h individually-rounded
// adds of w2[c][h] over spiking h — identical numerics to the validated l2.
// ---------------------------------------------------------------------------
__global__ __launch_bounds__(256)
void snn_l2a(const ulonglong2* __restrict__ masks,
             const float* __restrict__ w2,
             float* __restrict__ cur2)
{
    __shared__ float w2s[H_DIM * C_OUT];   // [h][c] for bank spread
    const int tid = threadIdx.x;
    for (int i = tid; i < H_DIM * C_OUT; i += 256) {
        const int c = i / H_DIM, h = i % H_DIM;
        w2s[h * C_OUT + c] = w2[i];
    }
    __syncthreads();

    const size_t gid = (size_t)blockIdx.x * 256 + tid;   // == t*B_TOTAL + b
    const ulonglong2 mk = masks[gid];
    float s0 = 0.f, s1 = 0.f, s2 = 0.f, s3 = 0.f, s4 = 0.f;

    auto acc32 = [&](uint32_t w, int base) {
        while (w) {
            const int h = base + __builtin_ctz(w);
            w &= w - 1;
            const float* wp = &w2s[h * C_OUT];
            s0 = __fadd_rn(s0, wp[0]);
            s1 = __fadd_rn(s1, wp[1]);
            s2 = __fadd_rn(s2, wp[2]);
            s3 = __fadd_rn(s3, wp[3]);
            s4 = __fadd_rn(s4, wp[4]);
        }
    };
    acc32((uint32_t)(mk.x & 0xffffffffull), 0);
    acc32((uint32_t)(mk.x >> 32), 32);
    acc32((uint32_t)(mk.y & 0xffffffffull), 64);
    acc32((uint32_t)(mk.y >> 32), 96);

    float* o = cur2 + gid * C_OUT;
    o[0] = s0; o[1] = s1; o[2] = s2; o[3] = s3; o[4] = s4;
}

// ---------------------------------------------------------------------------
// Kernel C: layer-2 recurrence over t. Lane = (b,c), coalesced cur2/out,
// depth-4 static-unrolled prefetch. Ops identical to validated l2.
// ---------------------------------------------------------------------------
__global__ __launch_bounds__(256)
void snn_l2b(const float* __restrict__ cur2,
             const float* __restrict__ b2,
             float* __restrict__ out)
{
    const int gid = blockIdx.x * 256 + threadIdx.x;      // b*5 + c
    const float b2c = b2[gid % 5];
    const int STRIDE = B_TOTAL * C_OUT;                  // 40960
    float m2 = 0.0f, r2 = 0.0f;

    float f0 = cur2[0 * (size_t)STRIDE + gid];
    float f1 = cur2[1 * (size_t)STRIDE + gid];
    float f2 = cur2[2 * (size_t)STRIDE + gid];
    float f3 = cur2[3 * (size_t)STRIDE + gid];

#define L2B_STEP(F, TT)                                                        \
    {                                                                          \
        const float cur = __fadd_rn(F, b2c);                                   \
        m2 = __fsub_rn(__fadd_rn(__fmul_rn(0.9f, m2), cur), r2);               \
        const float s = (m2 > 1.0f) ? 1.0f : 0.0f;                             \
        r2 = s;                                                                \
        out[(size_t)(TT) * STRIDE + gid] = s;                                  \
        F = ((TT) + 4 < T_STEPS) ? cur2[(size_t)((TT) + 4) * STRIDE + gid]     \
                                 : 0.0f;                                       \
    }

    for (int t = 0; t < T_STEPS; t += 4) {
        L2B_STEP(f0, t + 0)
        L2B_STEP(f1, t + 1)
        L2B_STEP(f2, t + 2)
        L2B_STEP(f3, t + 3)
    }
#undef L2B_STEP
}

extern "C" void kernel_launch(void* const* d_in, const int* in_sizes, int n_in,
                              void* d_out, int out_size, void* d_ws, size_t ws_size,
                              hipStream_t stream) {
    const float* x  = (const float*)d_in[0];
    const float* w1 = (const float*)d_in[1];
    const float* b1 = (const float*)d_in[2];
    const float* w2 = (const float*)d_in[3];
    const float* b2 = (const float*)d_in[4];
    float* out = (float*)d_out;

    // ws layout: masks [t][b] 16B = 26,214,400 B; cur2 [t][b][c] fp32 =
    // 32,768,000 B; wpairs 64*40*8 = 20,480 B.  Total ~59 MB.
    ulonglong2* masks = (ulonglong2*)d_ws;
    float* cur2 = (float*)((char*)d_ws + (size_t)T_STEPS * B_TOTAL * 16);
    v2f* wpairs = (v2f*)((char*)d_ws + (size_t)T_STEPS * B_TOTAL * 16
                                     + (size_t)T_STEPS * B_TOTAL * C_OUT * 4);

    prep_w <<<dim3(10),                      dim3(256), 0, stream>>>(w1, wpairs);
    snn_l1 <<<dim3(B_TOTAL / 4),             dim3(256), 0, stream>>>(x, wpairs, b1, masks);
    snn_l2a<<<dim3(T_STEPS * B_TOTAL / 256), dim3(256), 0, stream>>>(masks, w2, cur2);
    snn_l2b<<<dim3(B_TOTAL * C_OUT / 256),   dim3(256), 0, stream>>>(cur2, b2, out);
}